// Round 2
// baseline (563.902 us; speedup 1.0000x reference)
//
#include <hip/hip_runtime.h>
#include <hip/hip_bf16.h>
#include <stdint.h>

typedef __attribute__((ext_vector_type(8))) short short8;
typedef __attribute__((ext_vector_type(4))) float floatx4;

#define NB 4
#define NN 8192
#define NC 768
#define NH 12
#define ND 64
#define LDQKV 2304

// ---------- helpers ----------
__device__ __forceinline__ float bf2f(ushort u) {
    union { float f; uint32_t i; } x; x.i = ((uint32_t)u) << 16; return x.f;
}
__device__ __forceinline__ ushort f2bf(float f) {
    union { float f; uint32_t i; } x; x.f = f;
    uint32_t r = x.i + 0x7fff + ((x.i >> 16) & 1);
    return (ushort)(r >> 16);
}
// async global->LDS, 16B per lane: lane i lands at ldsbase + 16*i (wave-uniform base).
typedef const __attribute__((address_space(1))) uint32_t* gas1_t;
typedef __attribute__((address_space(3))) uint32_t* las3_t;
__device__ __forceinline__ void gl_lds16(const void* g, const void* l) {
    __builtin_amdgcn_global_load_lds((gas1_t)(uintptr_t)g,
                                     (las3_t)(uint32_t)(uintptr_t)l, 16, 0, 0);
}

// ---------- fp32 -> bf16 bulk convert (8 elems/thread, 16B stores) ----------
__global__ __launch_bounds__(256) void cvt_bf16(const float* __restrict__ src,
                                                ushort* __restrict__ dst, int n) {
    const int i = (blockIdx.x * 256 + threadIdx.x) * 8;
    if (i >= n) return;
    const float4 a = *(const float4*)(src + i);
    const float4 b = *(const float4*)(src + i + 4);
    short8 v;
    v[0] = (short)f2bf(a.x); v[1] = (short)f2bf(a.y);
    v[2] = (short)f2bf(a.z); v[3] = (short)f2bf(a.w);
    v[4] = (short)f2bf(b.x); v[5] = (short)f2bf(b.y);
    v[6] = (short)f2bf(b.z); v[7] = (short)f2bf(b.w);
    *(short8*)(dst + i) = v;
}

// ---------- 256x256 GEMM: C = act(A[M,K] @ Bw[N,K]^T (+bias)) ----------
// 512 threads = 8 waves (2M x 4N); per-wave 128x64 out; BK=64; 128 KiB LDS.
// v2: ds_reads hoisted out of the barrier lockstep (compiler-counted lgkmcnt
// overlaps read latency with MFMA); ONE barrier per phase (after MFMA);
// counted vmcnt(4) once per K-tile. LDS XOR-swizzle on stage-source + reads.

// stage one 128x64 half-tile (2 x gl_lds16 per thread), source-side swizzle
__device__ __forceinline__ void stage_half(const ushort* __restrict__ src, int row0,
                                           int k0, int K, ushort* dst, int t, int w) {
    const int rsub = t >> 3;                       // 0..63
    const int ch = (t & 7) ^ (rsub & 7);           // inverse of read-side XOR
    const ushort* g0 = src + (size_t)(row0 + rsub) * K + k0 + ch * 8;
    gl_lds16(g0,                 dst + w * 512);
    gl_lds16(g0 + (size_t)64 * K, dst + 4096 + w * 512);
}

template<int LDC, bool ELU, bool BIAS, typename OutT>
__global__ __launch_bounds__(512) void gemm256(const ushort* __restrict__ A,
                                               const ushort* __restrict__ Bw,
                                               const float* __restrict__ bias,
                                               OutT* __restrict__ Cout, int K) {
    __shared__ __align__(16) ushort SL[2][4][8192];   // [buf][region][128*64]
    const int t = threadIdx.x, w = t >> 6, lane = t & 63;
    const int l16 = lane & 15, quad = lane >> 4;
    const int wm = w >> 2, wn = w & 3;
    const int bro = (wn & 1) * 64;                    // row offset inside B region

    const int gx = gridDim.x;
    const int nwg = gx * gridDim.y;
    int bid = blockIdx.y * gx + blockIdx.x;
    bid = (bid & 7) * (nwg >> 3) + (bid >> 3);        // XCD swizzle (nwg % 8 == 0)
    const int m0 = (bid / gx) * 256;
    const int n0 = (bid % gx) * 256;
    const int NT = K >> 6;                            // K-tiles of 64 (NT >= 3)

    floatx4 acc[8][4] = {};

    // prologue: K0 {B0,B1,A0,A1}, K1 {B0,B1}  -> 12 loads/thread
    stage_half(Bw, n0,       0,  K, &SL[0][0][0], t, w);
    stage_half(Bw, n0 + 128, 0,  K, &SL[0][1][0], t, w);
    stage_half(A,  m0,       0,  K, &SL[0][2][0], t, w);
    stage_half(A,  m0 + 128, 0,  K, &SL[0][3][0], t, w);
    stage_half(Bw, n0,       64, K, &SL[1][0][0], t, w);
    stage_half(Bw, n0 + 128, 64, K, &SL[1][1][0], t, w);
    asm volatile("s_waitcnt vmcnt(4)" ::: "memory");  // K0 fully resident
    __builtin_amdgcn_s_barrier();

    for (int j = 0; j < NT; j++) {
        const int buf = j & 1;
        const ushort* As = &SL[buf][2 + wm][0];
        const ushort* Bs = &SL[buf][wn >> 1][0];
        short8 afl[4][2], afh[4][2], b01[2][2], b23[2][2];

        // ---- iteration-top reads: afl + b01 + b23 (16 x ds_read_b128).
        // Buffer is resident all iteration; compiler-counted lgkmcnt lets the
        // b23 latency hide under g0's MFMA.
        #pragma unroll
        for (int mi = 0; mi < 4; mi++) {
            const int row = mi * 16 + l16;
            const int sw = (row & 7) << 3;
            const int base = row * 64 + quad * 8;
            afl[mi][0] = *(const short8*)&As[base ^ sw];
            afl[mi][1] = *(const short8*)&As[(base + 32) ^ sw];
        }
        #pragma unroll
        for (int ni = 0; ni < 2; ni++) {
            const int row = bro + ni * 16 + l16;
            const int sw = (row & 7) << 3;
            const int base = row * 64 + quad * 8;
            b01[ni][0] = *(const short8*)&Bs[base ^ sw];
            b01[ni][1] = *(const short8*)&Bs[(base + 32) ^ sw];
        }
        #pragma unroll
        for (int ni = 0; ni < 2; ni++) {
            const int row = bro + (2 + ni) * 16 + l16;
            const int sw = (row & 7) << 3;
            const int base = row * 64 + quad * 8;
            b23[ni][0] = *(const short8*)&Bs[base ^ sw];
            b23[ni][1] = *(const short8*)&Bs[(base + 32) ^ sw];
        }

        // ---- phase 0: stage A-lo(j+1); MFMA m_lo x n01
        if (j + 1 < NT) stage_half(A, m0, (j + 1) * 64, K, &SL[buf ^ 1][2][0], t, w);
        __builtin_amdgcn_s_setprio(1);
        #pragma unroll
        for (int mi = 0; mi < 4; mi++)
            #pragma unroll
            for (int ni = 0; ni < 2; ni++) {
                acc[mi][ni] = __builtin_amdgcn_mfma_f32_16x16x32_bf16(afl[mi][0], b01[ni][0], acc[mi][ni], 0, 0, 0);
                acc[mi][ni] = __builtin_amdgcn_mfma_f32_16x16x32_bf16(afl[mi][1], b01[ni][1], acc[mi][ni], 0, 0, 0);
            }
        __builtin_amdgcn_s_setprio(0);
        __builtin_amdgcn_s_barrier();

        // ---- phase 1: read afh (hides under g1); stage A-hi(j+1); MFMA m_lo x n23
        #pragma unroll
        for (int mi = 0; mi < 4; mi++) {
            const int row = (4 + mi) * 16 + l16;
            const int sw = (row & 7) << 3;
            const int base = row * 64 + quad * 8;
            afh[mi][0] = *(const short8*)&As[base ^ sw];
            afh[mi][1] = *(const short8*)&As[(base + 32) ^ sw];
        }
        if (j + 1 < NT) stage_half(A, m0 + 128, (j + 1) * 64, K, &SL[buf ^ 1][3][0], t, w);
        __builtin_amdgcn_s_setprio(1);
        #pragma unroll
        for (int mi = 0; mi < 4; mi++)
            #pragma unroll
            for (int ni = 0; ni < 2; ni++) {
                acc[mi][2 + ni] = __builtin_amdgcn_mfma_f32_16x16x32_bf16(afl[mi][0], b23[ni][0], acc[mi][2 + ni], 0, 0, 0);
                acc[mi][2 + ni] = __builtin_amdgcn_mfma_f32_16x16x32_bf16(afl[mi][1], b23[ni][1], acc[mi][2 + ni], 0, 0, 0);
            }
        __builtin_amdgcn_s_setprio(0);
        __builtin_amdgcn_s_barrier();

        // ---- phase 2: stage B-lo(j+2); MFMA m_hi x n01
        if (j + 2 < NT) stage_half(Bw, n0, (j + 2) * 64, K, &SL[buf][0][0], t, w);
        __builtin_amdgcn_s_setprio(1);
        #pragma unroll
        for (int mi = 0; mi < 4; mi++)
            #pragma unroll
            for (int ni = 0; ni < 2; ni++) {
                acc[4 + mi][ni] = __builtin_amdgcn_mfma_f32_16x16x32_bf16(afh[mi][0], b01[ni][0], acc[4 + mi][ni], 0, 0, 0);
                acc[4 + mi][ni] = __builtin_amdgcn_mfma_f32_16x16x32_bf16(afh[mi][1], b01[ni][1], acc[4 + mi][ni], 0, 0, 0);
            }
        __builtin_amdgcn_s_setprio(0);
        __builtin_amdgcn_s_barrier();

        // ---- phase 3: stage B-hi(j+2); MFMA m_hi x n23; boundary vmcnt
        if (j + 2 < NT) stage_half(Bw, n0 + 128, (j + 2) * 64, K, &SL[buf][1][0], t, w);
        __builtin_amdgcn_s_setprio(1);
        #pragma unroll
        for (int mi = 0; mi < 4; mi++)
            #pragma unroll
            for (int ni = 0; ni < 2; ni++) {
                acc[4 + mi][2 + ni] = __builtin_amdgcn_mfma_f32_16x16x32_bf16(afh[mi][0], b23[ni][0], acc[4 + mi][2 + ni], 0, 0, 0);
                acc[4 + mi][2 + ni] = __builtin_amdgcn_mfma_f32_16x16x32_bf16(afh[mi][1], b23[ni][1], acc[4 + mi][2 + ni], 0, 0, 0);
            }
        __builtin_amdgcn_s_setprio(0);
        // tile j+1 must be resident after this barrier; leave B(j+2) in flight
        if (j < NT - 2) asm volatile("s_waitcnt vmcnt(4)" ::: "memory");
        else            asm volatile("s_waitcnt vmcnt(0)" ::: "memory");
        __builtin_amdgcn_s_barrier();
    }

    // ---- epilogue
    #pragma unroll
    for (int mi = 0; mi < 8; mi++) {
        const int row = m0 + wm * 128 + mi * 16 + quad * 4;
        #pragma unroll
        for (int n = 0; n < 4; n++) {
            const int col = n0 + wn * 64 + n * 16 + l16;
            float bval = 0.f;
            if (BIAS) bval = bias[col];
            #pragma unroll
            for (int r = 0; r < 4; r++) {
                float v = acc[mi][n][r];
                if (ELU) { if (col < 2 * NC) v = (v > 0.f) ? v + 1.f : __expf(v); }
                if (BIAS) v += bval;
                if (sizeof(OutT) == 2) Cout[(size_t)(row + r) * LDC + col] = (OutT)f2bf(v);
                else                   Cout[(size_t)(row + r) * LDC + col] = (OutT)v;
            }
        }
    }
}

// ---------- kv_part[c][bh][d][e] = sum_n k[n,d] v[n,e] over n-chunk c; also ksum ----------
// v2: no global/LDS atomics (barrier-tree reduce, non-atomic partials);
// ksum via MFMA against all-ones B instead of a 256-iter serial scalar loop.
__global__ __launch_bounds__(256) void kv_ksum(const ushort* __restrict__ qkv,
                                               float* __restrict__ kv_part,
                                               float* __restrict__ ks_part) {
    __shared__ ushort kvsh[2][128 * 64];   // klds / vlds; reused as f32 scratch
    __shared__ float  ksred[4][64];
    ushort* klds = kvsh[0];
    ushort* vlds = kvsh[1];
    const int bh = blockIdx.y, b = bh / NH, h = bh % NH;
    const int t = threadIdx.x, w = t >> 6, lane = t & 63, l16 = lane & 15, quad = lane >> 4;
    const int n0 = blockIdx.x * 1024;
    const ushort* kbase = qkv + (size_t)(b * NN) * LDQKV + NC     + h * ND;
    const ushort* vbase = qkv + (size_t)(b * NN) * LDQKV + 2 * NC + h * ND;

    floatx4 acc[4][4] = {};
    floatx4 aks[4] = {};
    short8 bones;
    #pragma unroll
    for (int j = 0; j < 8; j++) bones[j] = (short)0x3F80;   // bf16 1.0
    const int rowT = t >> 3, ch = t & 7;   // 32 rows x 8 chunks of 16B per issue

    for (int s = 0; s < 8; s++) {
        const int nb = n0 + s * 128;
        #pragma unroll
        for (int i = 0; i < 4; i++) {
            const size_t r = (size_t)(nb + i * 32 + rowT) * LDQKV + ch * 8;
            gl_lds16(kbase + r, klds + i * 2048 + w * 512);
            gl_lds16(vbase + r, vlds + i * 2048 + w * 512);
        }
        __syncthreads();
        short8 af[4], bfr[4];
        #pragma unroll
        for (int dt = 0; dt < 4; dt++) {
            short8 v;
            #pragma unroll
            for (int j = 0; j < 8; j++)
                v[j] = (short)klds[(w * 32 + quad * 8 + j) * 64 + dt * 16 + l16];
            af[dt] = v;
        }
        #pragma unroll
        for (int et = 0; et < 4; et++) {
            short8 v;
            #pragma unroll
            for (int j = 0; j < 8; j++)
                v[j] = (short)vlds[(w * 32 + quad * 8 + j) * 64 + et * 16 + l16];
            bfr[et] = v;
        }
        #pragma unroll
        for (int dt = 0; dt < 4; dt++) {
            #pragma unroll
            for (int et = 0; et < 4; et++)
                acc[dt][et] = __builtin_amdgcn_mfma_f32_16x16x32_bf16(af[dt], bfr[et], acc[dt][et], 0, 0, 0);
            aks[dt] = __builtin_amdgcn_mfma_f32_16x16x32_bf16(af[dt], bones, aks[dt], 0, 0, 0);
        }
        __syncthreads();
    }

    // ksum wave partials: lane l16==0 holds ksum[dt*16+quad*4+r] (dup over cols)
    if (l16 == 0) {
        #pragma unroll
        for (int dt = 0; dt < 4; dt++)
            #pragma unroll
            for (int r = 0; r < 4; r++)
                ksred[w][dt * 16 + quad * 4 + r] = aks[dt][r];
    }

    // kv barrier-tree reduce across the 4 waves via LDS scratch (no atomics)
    float* scratch = (float*)kvsh;         // 8192 floats
    if (w >= 2) {
        float* dst = scratch + (w - 2) * 4096;
        #pragma unroll
        for (int dt = 0; dt < 4; dt++)
            #pragma unroll
            for (int et = 0; et < 4; et++)
                #pragma unroll
                for (int r = 0; r < 4; r++)
                    dst[(dt * 16 + quad * 4 + r) * 64 + et * 16 + l16] = acc[dt][et][r];
    }
    __syncthreads();
    if (w < 2) {
        const float* srcp = scratch + w * 4096;
        #pragma unroll
        for (int dt = 0; dt < 4; dt++)
            #pragma unroll
            for (int et = 0; et < 4; et++)
                #pragma unroll
                for (int r = 0; r < 4; r++)
                    acc[dt][et][r] += srcp[(dt * 16 + quad * 4 + r) * 64 + et * 16 + l16];
    }
    __syncthreads();
    if (w == 1) {
        #pragma unroll
        for (int dt = 0; dt < 4; dt++)
            #pragma unroll
            for (int et = 0; et < 4; et++)
                #pragma unroll
                for (int r = 0; r < 4; r++)
                    scratch[(dt * 16 + quad * 4 + r) * 64 + et * 16 + l16] = acc[dt][et][r];
    }
    __syncthreads();
    if (w == 0) {
        float* outp = kv_part + ((size_t)blockIdx.x * 48 + bh) * 4096;
        #pragma unroll
        for (int dt = 0; dt < 4; dt++)
            #pragma unroll
            for (int et = 0; et < 4; et++)
                #pragma unroll
                for (int r = 0; r < 4; r++) {
                    const int idx = (dt * 16 + quad * 4 + r) * 64 + et * 16 + l16;
                    outp[idx] = acc[dt][et][r] + scratch[idx];
                }
    }
    if (t < 64) ks_part[(size_t)blockIdx.x * 48 * 64 + bh * 64 + t] =
        ksred[0][t] + ksred[1][t] + ksred[2][t] + ksred[3][t];
}

// ---------- out_pre[b,n,h*64+e] = (q[n,:] @ kv) / (q[n,:]·ksum + 1e-6), bf16 ----------
__global__ __launch_bounds__(256) void attn_apply(const ushort* __restrict__ qkv,
                                                  const float* __restrict__ kv_part,
                                                  const float* __restrict__ ks_part,
                                                  ushort* __restrict__ outpre) {
    __shared__ ushort kvb[64 * 80];
    const int bh = blockIdx.y, b = bh / NH, h = bh % NH;
    const int t = threadIdx.x, w = t >> 6, lane = t & 63, l16 = lane & 15, quad = lane >> 4;

    for (int i = t; i < 4096; i += 256) {
        float s = 0.f;
        #pragma unroll
        for (int c = 0; c < 8; c++) s += kv_part[((size_t)c * 48 + bh) * 4096 + i];
        kvb[(i >> 6) * 80 + (i & 63)] = f2bf(s);
    }
    for (int i = t; i < 1024; i += 256) {
        const int d = i >> 4, c = i & 15;
        float s = 0.f;
        if (c == 0) {
            #pragma unroll
            for (int cc = 0; cc < 8; cc++) s += ks_part[(size_t)cc * 48 * 64 + bh * 64 + d];
        }
        kvb[d * 80 + 64 + c] = (c == 0) ? f2bf(s) : (ushort)0;
    }
    __syncthreads();

    short8 bfr[5][2];
    #pragma unroll
    for (int et = 0; et < 5; et++)
        #pragma unroll
        for (int ks = 0; ks < 2; ks++) {
            short8 v;
            #pragma unroll
            for (int j = 0; j < 8; j++)
                v[j] = (short)kvb[(ks * 32 + quad * 8 + j) * 80 + et * 16 + l16];
            bfr[et][ks] = v;
        }

    const ushort* qbase = qkv + (size_t)(b * NN) * LDQKV + h * ND;
    ushort* obase = outpre + (size_t)(b * NN) * NC + h * ND;
    const int n0 = blockIdx.x * 1024;

    for (int it = 0; it < 16; it++) {
        const int nt = n0 + (it * 4 + w) * 16;
        const ushort* qp = qbase + (size_t)(nt + l16) * LDQKV + quad * 8;
        const short8 a0 = *(const short8*)qp;
        const short8 a1 = *(const short8*)(qp + 32);
        floatx4 acc[5] = {};
        #pragma unroll
        for (int et = 0; et < 5; et++) {
            acc[et] = __builtin_amdgcn_mfma_f32_16x16x32_bf16(a0, bfr[et][0], acc[et], 0, 0, 0);
            acc[et] = __builtin_amdgcn_mfma_f32_16x16x32_bf16(a1, bfr[et][1], acc[et], 0, 0, 0);
        }
        float dv[4];
        #pragma unroll
        for (int r = 0; r < 4; r++) dv[r] = __shfl(acc[4][r], lane & 48);
        #pragma unroll
        for (int et = 0; et < 4; et++)
            #pragma unroll
            for (int r = 0; r < 4; r++) {
                const float o = acc[et][r] / (dv[r] + 1e-6f);
                obase[(size_t)(nt + quad * 4 + r) * NC + et * 16 + l16] = f2bf(o);
            }
    }
}

extern "C" void kernel_launch(void* const* d_in, const int* in_sizes, int n_in,
                              void* d_out, int out_size, void* d_ws, size_t ws_size,
                              hipStream_t stream) {
    (void)in_sizes; (void)n_in; (void)out_size; (void)ws_size;
    const float* X     = (const float*)d_in[0];   // [4,8192,768] fp32
    const float* Wqkv  = (const float*)d_in[1];   // [2304,768]   fp32
    const float* Wproj = (const float*)d_in[2];   // [768,768]    fp32
    const float* bproj = (const float*)d_in[3];   // [768]        fp32
    float* out = (float*)d_out;                   // [4,8192,768] fp32

    char* ws = (char*)d_ws;
    size_t off = 0;
    ushort* qkv     = (ushort*)(ws + off); off += (size_t)32768 * 2304 * 2;  // 150,994,944
    ushort* outpre  = (ushort*)(ws + off); off += (size_t)32768 * 768 * 2;   //  50,331,648
    ushort* xbf     = (ushort*)(ws + off); off += (size_t)32768 * 768 * 2;   //  50,331,648
    ushort* wqkvbf  = (ushort*)(ws + off); off += (size_t)2304 * 768 * 2;    //   3,538,944
    ushort* wprojbf = (ushort*)(ws + off);                                    //   1,179,648
    // kv/ks partials alias xbf's space: xbf is dead once the QKV GEMM finishes,
    // kv_ksum runs strictly after it (stream order).  6.34 MB << 50 MB.
    float* kv_part = (float*)xbf;                          // [8][48][4096] f32
    float* ks_part = kv_part + (size_t)8 * 48 * 4096;      // [8][48][64]   f32

    const int nx = 32768 * 768, nwq = 2304 * 768, nwp = 768 * 768;
    cvt_bf16<<<nx  / (256 * 8), 256, 0, stream>>>(X,     xbf,     nx);
    cvt_bf16<<<nwq / (256 * 8), 256, 0, stream>>>(Wqkv,  wqkvbf,  nwq);
    cvt_bf16<<<nwp / (256 * 8), 256, 0, stream>>>(Wproj, wprojbf, nwp);

    // QKV: M=32768, N=2304 -> grid 9 x 128 = 1152 wgs (%8==0 for XCD swizzle)
    gemm256<LDQKV, true, false, ushort><<<dim3(9, 128), 512, 0, stream>>>(xbf, wqkvbf, nullptr, qkv, NC);
    kv_ksum<<<dim3(8, 48), 256, 0, stream>>>(qkv, kv_part, ks_part);
    attn_apply<<<dim3(8, 48), 256, 0, stream>>>(qkv, kv_part, ks_part, outpre);
    // proj: M=32768, N=768 -> grid 3 x 128 = 384 wgs
    gemm256<NC, false, true, float><<<dim3(3, 128), 512, 0, stream>>>(outpre, wprojbf, bproj, out, NC);
}

// Round 3
// 441.518 us; speedup vs baseline: 1.2772x; 1.2772x over previous
//
#include <hip/hip_runtime.h>
#include <hip/hip_bf16.h>
#include <stdint.h>

typedef __attribute__((ext_vector_type(8))) short short8;
typedef __attribute__((ext_vector_type(4))) float floatx4;

#define NB 4
#define NN 8192
#define NC 768
#define NH 12
#define ND 64
#define LDQKV 2304

// ---------- helpers ----------
__device__ __forceinline__ float bf2f(ushort u) {
    union { float f; uint32_t i; } x; x.i = ((uint32_t)u) << 16; return x.f;
}
__device__ __forceinline__ ushort f2bf(float f) {
    union { float f; uint32_t i; } x; x.f = f;
    uint32_t r = x.i + 0x7fff + ((x.i >> 16) & 1);
    return (ushort)(r >> 16);
}
// async global->LDS, 16B per lane: lane i lands at ldsbase + 16*i (wave-uniform base).
typedef const __attribute__((address_space(1))) uint32_t* gas1_t;
typedef __attribute__((address_space(3))) uint32_t* las3_t;
__device__ __forceinline__ void gl_lds16(const void* g, const void* l) {
    __builtin_amdgcn_global_load_lds((gas1_t)(uintptr_t)g,
                                     (las3_t)(uint32_t)(uintptr_t)l, 16, 0, 0);
}

// ---------- fp32 -> bf16 bulk convert (8 elems/thread, 16B stores) ----------
__global__ __launch_bounds__(256) void cvt_bf16(const float* __restrict__ src,
                                                ushort* __restrict__ dst, int n) {
    const int i = (blockIdx.x * 256 + threadIdx.x) * 8;
    if (i >= n) return;
    const float4 a = *(const float4*)(src + i);
    const float4 b = *(const float4*)(src + i + 4);
    short8 v;
    v[0] = (short)f2bf(a.x); v[1] = (short)f2bf(a.y);
    v[2] = (short)f2bf(a.z); v[3] = (short)f2bf(a.w);
    v[4] = (short)f2bf(b.x); v[5] = (short)f2bf(b.y);
    v[6] = (short)f2bf(b.z); v[7] = (short)f2bf(b.w);
    *(short8*)(dst + i) = v;
}

// ============ 256x256 8-phase GEMM (QKV): C = act(A @ Bw^T) ============
// 512 threads = 8 waves (2M x 4N); per-wave 128x64 out; BK=64; 128 KiB LDS.
// Two-barrier phase lockstep (R1 structure — R2's hoisted-read variant
// regressed 38%, do not deviate). Counted vmcnt(4) once per K-tile.
// LDS XOR-swizzle on stage-source + reads (T2; conflicts measured 0).

// stage one 128x64 half-tile (2 x gl_lds16 per thread), source-side swizzle
__device__ __forceinline__ void stage_half(const ushort* __restrict__ src, int row0,
                                           int k0, int K, ushort* dst, int t, int w) {
    const int rsub = t >> 3;                       // 0..63
    const int ch = (t & 7) ^ (rsub & 7);           // inverse of read-side XOR
    const ushort* g0 = src + (size_t)(row0 + rsub) * K + k0 + ch * 8;
    gl_lds16(g0,                 dst + w * 512);
    gl_lds16(g0 + (size_t)64 * K, dst + 4096 + w * 512);
}

#define PHASE_SYNC() do {                                        \
    __builtin_amdgcn_s_barrier();                                \
    asm volatile("s_waitcnt lgkmcnt(0)" ::: "memory");           \
    __builtin_amdgcn_sched_barrier(0);                           \
} while (0)

template<int LDC, bool ELU, bool BIAS, typename OutT>
__global__ __launch_bounds__(512) void gemm256(const ushort* __restrict__ A,
                                               const ushort* __restrict__ Bw,
                                               const float* __restrict__ bias,
                                               OutT* __restrict__ Cout, int K) {
    __shared__ __align__(16) ushort SL[2][4][8192];   // [buf][region][128*64]
    const int t = threadIdx.x, w = t >> 6, lane = t & 63;
    const int l16 = lane & 15, quad = lane >> 4;
    const int wm = w >> 2, wn = w & 3;
    const int bro = (wn & 1) * 64;                    // row offset inside B region

    const int gx = gridDim.x;
    const int nwg = gx * gridDim.y;
    int bid = blockIdx.y * gx + blockIdx.x;
    bid = (bid & 7) * (nwg >> 3) + (bid >> 3);        // XCD swizzle (nwg % 8 == 0)
    const int m0 = (bid / gx) * 256;
    const int n0 = (bid % gx) * 256;
    const int NT = K >> 6;                            // K-tiles of 64 (NT >= 3)

    floatx4 acc[8][4] = {};
    short8 af[4][2], b01[2][2], b23[2][2];

    // prologue: K0 {B0,B1,A0,A1}, K1 {B0,B1}  -> 12 loads/thread
    stage_half(Bw, n0,       0,  K, &SL[0][0][0], t, w);
    stage_half(Bw, n0 + 128, 0,  K, &SL[0][1][0], t, w);
    stage_half(A,  m0,       0,  K, &SL[0][2][0], t, w);
    stage_half(A,  m0 + 128, 0,  K, &SL[0][3][0], t, w);
    stage_half(Bw, n0,       64, K, &SL[1][0][0], t, w);
    stage_half(Bw, n0 + 128, 64, K, &SL[1][1][0], t, w);
    asm volatile("s_waitcnt vmcnt(4)" ::: "memory");  // K0 fully resident
    __builtin_amdgcn_s_barrier();

    for (int j = 0; j < NT; j++) {
        const int buf = j & 1;
        const ushort* As = &SL[buf][2 + wm][0];
        const ushort* Bs = &SL[buf][wn >> 1][0];

        // ---- phase 0: read A(m_lo) + B(n0,n1) [12 ds_reads]; stage A-lo(j+1)
        #pragma unroll
        for (int mi = 0; mi < 4; mi++) {
            const int row = mi * 16 + l16;
            const int sw = (row & 7) << 3;
            const int base = row * 64 + quad * 8;
            af[mi][0] = *(const short8*)&As[base ^ sw];
            af[mi][1] = *(const short8*)&As[(base + 32) ^ sw];
        }
        #pragma unroll
        for (int ni = 0; ni < 2; ni++) {
            const int row = bro + ni * 16 + l16;
            const int sw = (row & 7) << 3;
            const int base = row * 64 + quad * 8;
            b01[ni][0] = *(const short8*)&Bs[base ^ sw];
            b01[ni][1] = *(const short8*)&Bs[(base + 32) ^ sw];
        }
        if (j + 1 < NT) stage_half(A, m0, (j + 1) * 64, K, &SL[buf ^ 1][2][0], t, w);
        asm volatile("s_waitcnt lgkmcnt(8)" ::: "memory");  // template hint: 12 reads issued
        PHASE_SYNC();
        __builtin_amdgcn_s_setprio(1);
        #pragma unroll
        for (int mi = 0; mi < 4; mi++)
            #pragma unroll
            for (int ni = 0; ni < 2; ni++) {
                acc[mi][ni] = __builtin_amdgcn_mfma_f32_16x16x32_bf16(af[mi][0], b01[ni][0], acc[mi][ni], 0, 0, 0);
                acc[mi][ni] = __builtin_amdgcn_mfma_f32_16x16x32_bf16(af[mi][1], b01[ni][1], acc[mi][ni], 0, 0, 0);
            }
        __builtin_amdgcn_s_setprio(0);
        __builtin_amdgcn_s_barrier();

        // ---- phase 1: read B(n2,n3); stage A-hi(j+1); MFMA m_lo x n23
        #pragma unroll
        for (int ni = 0; ni < 2; ni++) {
            const int row = bro + (2 + ni) * 16 + l16;
            const int sw = (row & 7) << 3;
            const int base = row * 64 + quad * 8;
            b23[ni][0] = *(const short8*)&Bs[base ^ sw];
            b23[ni][1] = *(const short8*)&Bs[(base + 32) ^ sw];
        }
        if (j + 1 < NT) stage_half(A, m0 + 128, (j + 1) * 64, K, &SL[buf ^ 1][3][0], t, w);
        PHASE_SYNC();
        __builtin_amdgcn_s_setprio(1);
        #pragma unroll
        for (int mi = 0; mi < 4; mi++)
            #pragma unroll
            for (int ni = 0; ni < 2; ni++) {
                acc[mi][2 + ni] = __builtin_amdgcn_mfma_f32_16x16x32_bf16(af[mi][0], b23[ni][0], acc[mi][2 + ni], 0, 0, 0);
                acc[mi][2 + ni] = __builtin_amdgcn_mfma_f32_16x16x32_bf16(af[mi][1], b23[ni][1], acc[mi][2 + ni], 0, 0, 0);
            }
        __builtin_amdgcn_s_setprio(0);
        __builtin_amdgcn_s_barrier();

        // ---- phase 2: read A(m_hi); stage B-lo(j+2); MFMA m_hi x n01
        #pragma unroll
        for (int mi = 0; mi < 4; mi++) {
            const int row = (4 + mi) * 16 + l16;
            const int sw = (row & 7) << 3;
            const int base = row * 64 + quad * 8;
            af[mi][0] = *(const short8*)&As[base ^ sw];
            af[mi][1] = *(const short8*)&As[(base + 32) ^ sw];
        }
        if (j + 2 < NT) stage_half(Bw, n0, (j + 2) * 64, K, &SL[buf][0][0], t, w);
        PHASE_SYNC();
        __builtin_amdgcn_s_setprio(1);
        #pragma unroll
        for (int mi = 0; mi < 4; mi++)
            #pragma unroll
            for (int ni = 0; ni < 2; ni++) {
                acc[4 + mi][ni] = __builtin_amdgcn_mfma_f32_16x16x32_bf16(af[mi][0], b01[ni][0], acc[4 + mi][ni], 0, 0, 0);
                acc[4 + mi][ni] = __builtin_amdgcn_mfma_f32_16x16x32_bf16(af[mi][1], b01[ni][1], acc[4 + mi][ni], 0, 0, 0);
            }
        __builtin_amdgcn_s_setprio(0);
        __builtin_amdgcn_s_barrier();

        // ---- phase 3: stage B-hi(j+2); MFMA m_hi x n23; boundary vmcnt
        if (j + 2 < NT) stage_half(Bw, n0 + 128, (j + 2) * 64, K, &SL[buf][1][0], t, w);
        __builtin_amdgcn_s_barrier();
        __builtin_amdgcn_s_setprio(1);
        #pragma unroll
        for (int mi = 0; mi < 4; mi++)
            #pragma unroll
            for (int ni = 0; ni < 2; ni++) {
                acc[4 + mi][2 + ni] = __builtin_amdgcn_mfma_f32_16x16x32_bf16(af[mi][0], b23[ni][0], acc[4 + mi][2 + ni], 0, 0, 0);
                acc[4 + mi][2 + ni] = __builtin_amdgcn_mfma_f32_16x16x32_bf16(af[mi][1], b23[ni][1], acc[4 + mi][2 + ni], 0, 0, 0);
            }
        __builtin_amdgcn_s_setprio(0);
        // tile j+1 must be resident after this barrier; leave B(j+2) in flight
        if (j < NT - 2) asm volatile("s_waitcnt vmcnt(4)" ::: "memory");
        else            asm volatile("s_waitcnt vmcnt(0)" ::: "memory");
        __builtin_amdgcn_s_barrier();
    }

    // ---- epilogue
    #pragma unroll
    for (int mi = 0; mi < 8; mi++) {
        const int row = m0 + wm * 128 + mi * 16 + quad * 4;
        #pragma unroll
        for (int n = 0; n < 4; n++) {
            const int col = n0 + wn * 64 + n * 16 + l16;
            float bval = 0.f;
            if (BIAS) bval = bias[col];
            #pragma unroll
            for (int r = 0; r < 4; r++) {
                float v = acc[mi][n][r];
                if (ELU) { if (col < 2 * NC) v = (v > 0.f) ? v + 1.f : __expf(v); }
                if (BIAS) v += bval;
                if (sizeof(OutT) == 2) Cout[(size_t)(row + r) * LDC + col] = (OutT)f2bf(v);
                else                   Cout[(size_t)(row + r) * LDC + col] = (OutT)v;
            }
        }
    }
}

// ============ 128x128 2-phase GEMM (proj): better tail at small N ============
// 256 threads (4 waves, 2x2), 4x4 16x16x32 MFMA per wave, BK=32, 16 KiB LDS
// -> 2 blocks/CU; grid 6x256 = 1536 blocks = 3 exact generations (no tail idle).
template<int LDC, bool ELU, bool BIAS, typename OutT>
__global__ __launch_bounds__(256) void gemm_bt(const ushort* __restrict__ A,
                                               const ushort* __restrict__ Bw,
                                               const float* __restrict__ bias,
                                               OutT* __restrict__ Cout, int K) {
    __shared__ ushort As[128 * 32];
    __shared__ ushort Bs[128 * 32];
    const int t = threadIdx.x;
    const int w = t >> 6, lane = t & 63, l16 = lane & 15, quad = lane >> 4;
    const int wm = w & 1, wn = w >> 1;
    const int m0 = blockIdx.y * 128, n0 = blockIdx.x * 128;

    floatx4 acc[4][4] = {};

    const int rowA = t >> 2, chA = t & 3;            // 64 rows x 4 chunks of 16B
    const ushort* gA = A  + (size_t)(m0 + rowA) * K + chA * 8;
    const ushort* gB = Bw + (size_t)(n0 + rowA) * K + chA * 8;

    for (int k0 = 0; k0 < K; k0 += 32) {
        gl_lds16(gA + k0,                As + w * 512);
        gl_lds16(gA + k0 + 64 * K,       As + 2048 + w * 512);
        gl_lds16(gB + k0,                Bs + w * 512);
        gl_lds16(gB + k0 + 64 * K,       Bs + 2048 + w * 512);
        __syncthreads();
        short8 af[4], bfr[4];
        #pragma unroll
        for (int i = 0; i < 4; i++)
            af[i] = *(const short8*)&As[(wm * 64 + i * 16 + l16) * 32 + quad * 8];
        #pragma unroll
        for (int j = 0; j < 4; j++)
            bfr[j] = *(const short8*)&Bs[(wn * 64 + j * 16 + l16) * 32 + quad * 8];
        #pragma unroll
        for (int i = 0; i < 4; i++)
            #pragma unroll
            for (int j = 0; j < 4; j++)
                acc[i][j] = __builtin_amdgcn_mfma_f32_16x16x32_bf16(af[i], bfr[j], acc[i][j], 0, 0, 0);
        __syncthreads();
    }

    #pragma unroll
    for (int i = 0; i < 4; i++) {
        const int row = m0 + wm * 64 + i * 16 + quad * 4;
        #pragma unroll
        for (int j = 0; j < 4; j++) {
            const int col = n0 + wn * 64 + j * 16 + l16;
            float bval = 0.f;
            if (BIAS) bval = bias[col];
            #pragma unroll
            for (int r = 0; r < 4; r++) {
                float v = acc[i][j][r];
                if (ELU) { if (col < 2 * NC) v = (v > 0.f) ? v + 1.f : __expf(v); }
                if (BIAS) v += bval;
                if (sizeof(OutT) == 2) Cout[(size_t)(row + r) * LDC + col] = (OutT)f2bf(v);
                else                   Cout[(size_t)(row + r) * LDC + col] = (OutT)v;
            }
        }
    }
}

// ---------- kv_part[c][bh][d][e] = sum_n k[n,d] v[n,e] over n-chunk c; also ksum ----------
// atomics-free: barrier-tree reduce in LDS, non-atomic per-block partials;
// ksum via MFMA against all-ones B (no serial scalar loop).
__global__ __launch_bounds__(256) void kv_ksum(const ushort* __restrict__ qkv,
                                               float* __restrict__ kv_part,
                                               float* __restrict__ ks_part) {
    __shared__ ushort kvsh[2][128 * 64];   // klds / vlds; reused as f32 scratch
    __shared__ float  ksred[4][64];
    ushort* klds = kvsh[0];
    ushort* vlds = kvsh[1];
    const int bh = blockIdx.y, b = bh / NH, h = bh % NH;
    const int t = threadIdx.x, w = t >> 6, lane = t & 63, l16 = lane & 15, quad = lane >> 4;
    const int n0 = blockIdx.x * 1024;
    const ushort* kbase = qkv + (size_t)(b * NN) * LDQKV + NC     + h * ND;
    const ushort* vbase = qkv + (size_t)(b * NN) * LDQKV + 2 * NC + h * ND;

    floatx4 acc[4][4] = {};
    floatx4 aks[4] = {};
    short8 bones;
    #pragma unroll
    for (int j = 0; j < 8; j++) bones[j] = (short)0x3F80;   // bf16 1.0
    const int rowT = t >> 3, ch = t & 7;   // 32 rows x 8 chunks of 16B per issue

    for (int s = 0; s < 8; s++) {
        const int nb = n0 + s * 128;
        #pragma unroll
        for (int i = 0; i < 4; i++) {
            const size_t r = (size_t)(nb + i * 32 + rowT) * LDQKV + ch * 8;
            gl_lds16(kbase + r, klds + i * 2048 + w * 512);
            gl_lds16(vbase + r, vlds + i * 2048 + w * 512);
        }
        __syncthreads();
        short8 af[4], bfr[4];
        #pragma unroll
        for (int dt = 0; dt < 4; dt++) {
            short8 v;
            #pragma unroll
            for (int j = 0; j < 8; j++)
                v[j] = (short)klds[(w * 32 + quad * 8 + j) * 64 + dt * 16 + l16];
            af[dt] = v;
        }
        #pragma unroll
        for (int et = 0; et < 4; et++) {
            short8 v;
            #pragma unroll
            for (int j = 0; j < 8; j++)
                v[j] = (short)vlds[(w * 32 + quad * 8 + j) * 64 + et * 16 + l16];
            bfr[et] = v;
        }
        #pragma unroll
        for (int dt = 0; dt < 4; dt++) {
            #pragma unroll
            for (int et = 0; et < 4; et++)
                acc[dt][et] = __builtin_amdgcn_mfma_f32_16x16x32_bf16(af[dt], bfr[et], acc[dt][et], 0, 0, 0);
            aks[dt] = __builtin_amdgcn_mfma_f32_16x16x32_bf16(af[dt], bones, aks[dt], 0, 0, 0);
        }
        __syncthreads();
    }

    // ksum wave partials: lane l16==0 holds ksum[dt*16+quad*4+r] (dup over cols)
    if (l16 == 0) {
        #pragma unroll
        for (int dt = 0; dt < 4; dt++)
            #pragma unroll
            for (int r = 0; r < 4; r++)
                ksred[w][dt * 16 + quad * 4 + r] = aks[dt][r];
    }

    // kv barrier-tree reduce across the 4 waves via LDS scratch (no atomics)
    float* scratch = (float*)kvsh;         // 8192 floats
    if (w >= 2) {
        float* dst = scratch + (w - 2) * 4096;
        #pragma unroll
        for (int dt = 0; dt < 4; dt++)
            #pragma unroll
            for (int et = 0; et < 4; et++)
                #pragma unroll
                for (int r = 0; r < 4; r++)
                    dst[(dt * 16 + quad * 4 + r) * 64 + et * 16 + l16] = acc[dt][et][r];
    }
    __syncthreads();
    if (w < 2) {
        const float* srcp = scratch + w * 4096;
        #pragma unroll
        for (int dt = 0; dt < 4; dt++)
            #pragma unroll
            for (int et = 0; et < 4; et++)
                #pragma unroll
                for (int r = 0; r < 4; r++)
                    acc[dt][et][r] += srcp[(dt * 16 + quad * 4 + r) * 64 + et * 16 + l16];
    }
    __syncthreads();
    if (w == 1) {
        #pragma unroll
        for (int dt = 0; dt < 4; dt++)
            #pragma unroll
            for (int et = 0; et < 4; et++)
                #pragma unroll
                for (int r = 0; r < 4; r++)
                    scratch[(dt * 16 + quad * 4 + r) * 64 + et * 16 + l16] = acc[dt][et][r];
    }
    __syncthreads();
    if (w == 0) {
        float* outp = kv_part + ((size_t)blockIdx.x * 48 + bh) * 4096;
        #pragma unroll
        for (int dt = 0; dt < 4; dt++)
            #pragma unroll
            for (int et = 0; et < 4; et++)
                #pragma unroll
                for (int r = 0; r < 4; r++) {
                    const int idx = (dt * 16 + quad * 4 + r) * 64 + et * 16 + l16;
                    outp[idx] = acc[dt][et][r] + scratch[idx];
                }
    }
    if (t < 64) ks_part[(size_t)blockIdx.x * 48 * 64 + bh * 64 + t] =
        ksred[0][t] + ksred[1][t] + ksred[2][t] + ksred[3][t];
}

// ---------- out_pre[b,n,h*64+e] = (q[n,:] @ kv) / (q[n,:]·ksum + 1e-6), bf16 ----------
__global__ __launch_bounds__(256) void attn_apply(const ushort* __restrict__ qkv,
                                                  const float* __restrict__ kv_part,
                                                  const float* __restrict__ ks_part,
                                                  ushort* __restrict__ outpre) {
    __shared__ ushort kvb[64 * 80];
    const int bh = blockIdx.y, b = bh / NH, h = bh % NH;
    const int t = threadIdx.x, w = t >> 6, lane = t & 63, l16 = lane & 15, quad = lane >> 4;

    for (int i = t; i < 4096; i += 256) {
        float s = 0.f;
        #pragma unroll
        for (int c = 0; c < 8; c++) s += kv_part[((size_t)c * 48 + bh) * 4096 + i];
        kvb[(i >> 6) * 80 + (i & 63)] = f2bf(s);
    }
    for (int i = t; i < 1024; i += 256) {
        const int d = i >> 4, c = i & 15;
        float s = 0.f;
        if (c == 0) {
            #pragma unroll
            for (int cc = 0; cc < 8; cc++) s += ks_part[(size_t)cc * 48 * 64 + bh * 64 + d];
        }
        kvb[d * 80 + 64 + c] = (c == 0) ? f2bf(s) : (ushort)0;
    }
    __syncthreads();

    short8 bfr[5][2];
    #pragma unroll
    for (int et = 0; et < 5; et++)
        #pragma unroll
        for (int ks = 0; ks < 2; ks++) {
            short8 v;
            #pragma unroll
            for (int j = 0; j < 8; j++)
                v[j] = (short)kvb[(ks * 32 + quad * 8 + j) * 80 + et * 16 + l16];
            bfr[et][ks] = v;
        }

    const ushort* qbase = qkv + (size_t)(b * NN) * LDQKV + h * ND;
    ushort* obase = outpre + (size_t)(b * NN) * NC + h * ND;
    const int n0 = blockIdx.x * 1024;

    for (int it = 0; it < 16; it++) {
        const int nt = n0 + (it * 4 + w) * 16;
        const ushort* qp = qbase + (size_t)(nt + l16) * LDQKV + quad * 8;
        const short8 a0 = *(const short8*)qp;
        const short8 a1 = *(const short8*)(qp + 32);
        floatx4 acc[5] = {};
        #pragma unroll
        for (int et = 0; et < 5; et++) {
            acc[et] = __builtin_amdgcn_mfma_f32_16x16x32_bf16(a0, bfr[et][0], acc[et], 0, 0, 0);
            acc[et] = __builtin_amdgcn_mfma_f32_16x16x32_bf16(a1, bfr[et][1], acc[et], 0, 0, 0);
        }
        float dv[4];
        #pragma unroll
        for (int r = 0; r < 4; r++) dv[r] = __shfl(acc[4][r], lane & 48);
        #pragma unroll
        for (int et = 0; et < 4; et++)
            #pragma unroll
            for (int r = 0; r < 4; r++) {
                const float o = acc[et][r] / (dv[r] + 1e-6f);
                obase[(size_t)(nt + quad * 4 + r) * NC + et * 16 + l16] = f2bf(o);
            }
    }
}

extern "C" void kernel_launch(void* const* d_in, const int* in_sizes, int n_in,
                              void* d_out, int out_size, void* d_ws, size_t ws_size,
                              hipStream_t stream) {
    (void)in_sizes; (void)n_in; (void)out_size; (void)ws_size;
    const float* X     = (const float*)d_in[0];   // [4,8192,768] fp32
    const float* Wqkv  = (const float*)d_in[1];   // [2304,768]   fp32
    const float* Wproj = (const float*)d_in[2];   // [768,768]    fp32
    const float* bproj = (const float*)d_in[3];   // [768]        fp32
    float* out = (float*)d_out;                   // [4,8192,768] fp32

    char* ws = (char*)d_ws;
    size_t off = 0;
    ushort* qkv     = (ushort*)(ws + off); off += (size_t)32768 * 2304 * 2;  // 150,994,944
    ushort* outpre  = (ushort*)(ws + off); off += (size_t)32768 * 768 * 2;   //  50,331,648
    ushort* xbf     = (ushort*)(ws + off); off += (size_t)32768 * 768 * 2;   //  50,331,648
    ushort* wqkvbf  = (ushort*)(ws + off); off += (size_t)2304 * 768 * 2;    //   3,538,944
    ushort* wprojbf = (ushort*)(ws + off);                                    //   1,179,648
    // kv/ks partials alias xbf's space: xbf is dead once the QKV GEMM finishes,
    // kv_ksum runs strictly after it (stream order).  6.34 MB << 50 MB.
    float* kv_part = (float*)xbf;                          // [8][48][4096] f32
    float* ks_part = kv_part + (size_t)8 * 48 * 4096;      // [8][48][64]   f32

    const int nx = 32768 * 768, nwq = 2304 * 768, nwp = 768 * 768;
    cvt_bf16<<<nx  / (256 * 8), 256, 0, stream>>>(X,     xbf,     nx);
    cvt_bf16<<<nwq / (256 * 8), 256, 0, stream>>>(Wqkv,  wqkvbf,  nwq);
    cvt_bf16<<<nwp / (256 * 8), 256, 0, stream>>>(Wproj, wprojbf, nwp);

    // QKV: M=32768, N=2304 -> grid 9 x 128 = 1152 wgs (%8==0 for XCD swizzle)
    gemm256<LDQKV, true, false, ushort><<<dim3(9, 128), 512, 0, stream>>>(xbf, wqkvbf, nullptr, qkv, NC);
    kv_ksum<<<dim3(8, 48), 256, 0, stream>>>(qkv, kv_part, ks_part);
    attn_apply<<<dim3(8, 48), 256, 0, stream>>>(qkv, kv_part, ks_part, outpre);
    // proj: M=32768, N=768 -> grid 6 x 256 = 1536 blocks, 2/CU -> 3 exact gens
    gemm_bt<NC, false, true, float><<<dim3(6, 256), 256, 0, stream>>>(outpre, wprojbf, bproj, out, NC);
}